// Round 1
// baseline (423.293 us; speedup 1.0000x reference)
//
#include <hip/hip_runtime.h>

// RNN: B=256, T=512, I=256, H=128, O=1000, fp32 in/out.
// Internals in fp16 (11-bit mantissa): W,x,h at 2^-12 rel err -> absmax ~4e-3,
// threshold 3.3e-2. Single MFMA product per tile (no hi/lo split).
// ws: xp[131072][128] fp32 = 64 MiB. h_last[r] overwrites xp[r*512+0][:] after
// the recurrence (each block's own rows, consumed at t=0 long before).

#define HID    128
#define TSTEPS 512
#define BATCH  256
#define INDIM  256
#define ODIM   1000

typedef _Float16 f16x8 __attribute__((ext_vector_type(8)));
typedef __fp16   fp16x2 __attribute__((ext_vector_type(2)));
typedef float    f32x4 __attribute__((ext_vector_type(4)));

__device__ __forceinline__ unsigned pk16(float a, float b) {
    union { fp16x2 h; unsigned u; } t;
    t.h = __builtin_amdgcn_cvt_pkrtz(a, b);   // packs 2 fp32 -> 2 fp16 (RTZ)
    return t.u;
}
// tanh without clamp: exp2 overflow->inf->rcp->0 gives +1; underflow->0 gives -1.
__device__ __forceinline__ float tanh_fast(float v) {
    float e = __expf(2.f * v);                 // v_mul + v_exp_f32
    float r = __builtin_amdgcn_rcpf(e + 1.f);  // v_add + v_rcp_f32
    return __builtin_fmaf(-2.f, r, 1.f);
}

// ---------------- Kernel 1: xp = x @ W_ih^T + (b_ih + b_hh) ----------------
// MFMA 16x16x32 f16, double-buffered LDS staging, fp16 conversion at stage time.
// LDS tile rows = 32 k-elems (64B) = four 16B chunks, XOR-swizzled c ^= (row&3).
__global__ __launch_bounds__(256) void k_phase1(const float* __restrict__ x,
                                                const float* __restrict__ Wih,
                                                const float* __restrict__ bih,
                                                const float* __restrict__ bhh,
                                                float* __restrict__ xp) {
    __shared__ __align__(16) _Float16 xs[2][4096];   // x tile fp16
    __shared__ __align__(16) _Float16 wsm[2][4096];  // W tile fp16

    const int tid  = threadIdx.x;
    const int wave = tid >> 6, lane = tid & 63;
    const int quad = lane >> 4, l16 = lane & 15;
    const int wm = wave >> 1, wn = wave & 1;
    const int m0 = blockIdx.x * 128;

    // staging geometry: li = q*256+tid -> row = li>>3 (0..127), c = li&7 (4-float units)
    int srow[4], scol[4], sdst[4];
#pragma unroll
    for (int q = 0; q < 4; q++) {
        int li = q * 256 + tid;
        srow[q] = li >> 3;
        scol[q] = li & 7;
        sdst[q] = srow[q] * 32 + ((((scol[q] >> 1) ^ srow[q]) & 3) << 3) + ((scol[q] & 1) << 2);
    }

    float bias_v[4];
#pragma unroll
    for (int nt = 0; nt < 4; nt++) {
        int j = wn * 64 + nt * 16 + l16;
        bias_v[nt] = bih[j] + bhh[j];
    }

    float4 rx[4], rw[4];
#define LOAD_STAGE(KC)                                                              \
    {                                                                               \
        _Pragma("unroll") for (int q = 0; q < 4; q++) {                             \
            rx[q] = *(const float4*)(x + (size_t)(m0 + srow[q]) * INDIM + (KC) * 32 + scol[q] * 4); \
            rw[q] = *(const float4*)(Wih + (size_t)srow[q] * INDIM + (KC) * 32 + scol[q] * 4);      \
        }                                                                           \
    }
#define WRITE_STAGE(BUF)                                                            \
    {                                                                               \
        _Pragma("unroll") for (int q = 0; q < 4; q++) {                             \
            uint2 px, pw;                                                           \
            px.x = pk16(rx[q].x, rx[q].y); px.y = pk16(rx[q].z, rx[q].w);           \
            pw.x = pk16(rw[q].x, rw[q].y); pw.y = pk16(rw[q].z, rw[q].w);           \
            *(uint2*)&xs[BUF][sdst[q]]  = px;                                       \
            *(uint2*)&wsm[BUF][sdst[q]] = pw;                                       \
        }                                                                           \
    }

    f32x4 acc[4][4];
#pragma unroll
    for (int mt = 0; mt < 4; mt++)
#pragma unroll
        for (int nt = 0; nt < 4; nt++) {
            acc[mt][nt].x = 0.f; acc[mt][nt].y = 0.f;
            acc[mt][nt].z = 0.f; acc[mt][nt].w = 0.f;
        }

    LOAD_STAGE(0);
    WRITE_STAGE(0);
    __syncthreads();

    for (int kc = 0; kc < 8; kc++) {
        const int b = kc & 1;
        if (kc < 7) LOAD_STAGE(kc + 1);

        f16x8 a[4], bw[4];
#pragma unroll
        for (int mt = 0; mt < 4; mt++) {
            int row = wm * 64 + mt * 16 + l16;
            a[mt] = *(const f16x8*)&xs[b][row * 32 + (((quad ^ row) & 3) << 3)];
        }
#pragma unroll
        for (int nt = 0; nt < 4; nt++) {
            int row = wn * 64 + nt * 16 + l16;
            bw[nt] = *(const f16x8*)&wsm[b][row * 32 + (((quad ^ row) & 3) << 3)];
        }
#pragma unroll
        for (int mt = 0; mt < 4; mt++)
#pragma unroll
            for (int nt = 0; nt < 4; nt++)
                acc[mt][nt] = __builtin_amdgcn_mfma_f32_16x16x32_f16(a[mt], bw[nt], acc[mt][nt], 0, 0, 0);

        if (kc < 7) WRITE_STAGE(b ^ 1);
        __syncthreads();
    }

    // C layout: col = l16, row = quad*4 + reg
#pragma unroll
    for (int mt = 0; mt < 4; mt++)
#pragma unroll
        for (int nt = 0; nt < 4; nt++)
#pragma unroll
            for (int reg = 0; reg < 4; reg++) {
                int row = m0 + wm * 64 + mt * 16 + quad * 4 + reg;
                xp[(size_t)row * HID + wn * 64 + nt * 16 + l16] = acc[mt][nt][reg] + bias_v[nt];
            }
#undef LOAD_STAGE
#undef WRITE_STAGE
}

// ---------------- Kernel 2: recurrence (transposed MFMA, 4 waves) -----------
// 16 blocks x 256 thr. Block b: batch rows [16b,16b+16) = LDS h rows m=l16.
// Operand-swapped MFMA: C[j][m] = sum_k W[j][k]*h[m][k], A = W_hh (persistent
// VGPR frags), B = h (LDS). Wave w owns j in [32w,32w+32) = 2 j-tiles.
// C layout (col=m=l16, row=j'=quad*4+reg): the 4 acc regs are CONSECUTIVE j at
// fixed m -> h write is ONE ds_write_b64, xp load is ONE dwordx4 per tile.
// Per step per CU: 16 ds_read_b128 + 8 ds_write_b64 (vs old 32 reads + 32 b16
// writes) -- halves the LDS pipe. B-frag reads use the proven XOR-chunk
// swizzle (byte chunk c ^= m within 256B row): conflict-free.
// Barrier is raw asm `s_waitcnt lgkmcnt(0); s_barrier` -- NO vmcnt drain, so
// the xp prefetch genuinely stays 4 steps (~1us) in flight, unlike
// __syncthreads whose implicit vmcnt(0) put xp load latency on every step.
// 2 h planes + 1 barrier/step: lgkmcnt(0) drains this step's reads before the
// barrier, so no wave can overwrite a plane another wave still reads.
#define RSTEP(TV, XI0, XI1, XC0, XC1, PB) {                                       \
    uint2 pw0, pw1;                                                               \
    pw0.x = pk16(tanh_fast(C0.x), tanh_fast(C0.y));                               \
    pw0.y = pk16(tanh_fast(C0.z), tanh_fast(C0.w));                               \
    pw1.x = pk16(tanh_fast(C1.x), tanh_fast(C1.y));                               \
    pw1.y = pk16(tanh_fast(C1.z), tanh_fast(C1.w));                               \
    *(uint2*)&hp[PB][waddr0] = pw0;                                               \
    *(uint2*)&hp[PB][waddr1] = pw1;                                               \
    if ((TV) + 4 < TSTEPS) {                                                      \
        XI0 = *(const f32x4*)(xpb + ((TV) + 4) * HID);                            \
        XI1 = *(const f32x4*)(xpb + ((TV) + 4) * HID + 16);                       \
    }                                                                             \
    asm volatile("s_waitcnt lgkmcnt(0)\n\ts_barrier" ::: "memory");               \
    f16x8 hB0 = *(const f16x8*)&hp[PB][raddr0];                                   \
    f16x8 hB1 = *(const f16x8*)&hp[PB][raddr1];                                   \
    f16x8 hB2 = *(const f16x8*)&hp[PB][raddr2];                                   \
    f16x8 hB3 = *(const f16x8*)&hp[PB][raddr3];                                   \
    f32x4 c0h = XC0, c1h = XC1, c0l, c1l;                                         \
    c0l.x = 0.f; c0l.y = 0.f; c0l.z = 0.f; c0l.w = 0.f;                           \
    c1l.x = 0.f; c1l.y = 0.f; c1l.z = 0.f; c1l.w = 0.f;                           \
    c0h = __builtin_amdgcn_mfma_f32_16x16x32_f16(Wf[0][0], hB0, c0h, 0, 0, 0);    \
    c1h = __builtin_amdgcn_mfma_f32_16x16x32_f16(Wf[1][0], hB0, c1h, 0, 0, 0);    \
    c0l = __builtin_amdgcn_mfma_f32_16x16x32_f16(Wf[0][2], hB2, c0l, 0, 0, 0);    \
    c1l = __builtin_amdgcn_mfma_f32_16x16x32_f16(Wf[1][2], hB2, c1l, 0, 0, 0);    \
    c0h = __builtin_amdgcn_mfma_f32_16x16x32_f16(Wf[0][1], hB1, c0h, 0, 0, 0);    \
    c1h = __builtin_amdgcn_mfma_f32_16x16x32_f16(Wf[1][1], hB1, c1h, 0, 0, 0);    \
    c0l = __builtin_amdgcn_mfma_f32_16x16x32_f16(Wf[0][3], hB3, c0l, 0, 0, 0);    \
    c1l = __builtin_amdgcn_mfma_f32_16x16x32_f16(Wf[1][3], hB3, c1l, 0, 0, 0);    \
    C0 = c0h + c0l; C1 = c1h + c1l;                                               \
}

__global__ __launch_bounds__(256) void k_rnn(const float* __restrict__ Whh,
                                             float* __restrict__ ws) {
    __shared__ __align__(16) _Float16 hp[2][16 * 128];
    const int tid  = threadIdx.x;
    const int wave = tid >> 6, lane = tid & 63;
    const int quad = lane >> 4, l16 = lane & 15;
    const int row  = blockIdx.x * 16 + l16;     // batch row (B-operand column)

    // A-frags (persistent): W[j][k], j = 32*wave + 16*jt + l16, k = kc*32+quad*8+i
    f16x8 Wf[2][4];
#pragma unroll
    for (int jt = 0; jt < 2; jt++)
#pragma unroll
        for (int kc = 0; kc < 4; kc++) {
            const float* p = Whh + (size_t)(32 * wave + 16 * jt + l16) * HID + kc * 32 + quad * 8;
            float4 e0 = *(const float4*)p, e1 = *(const float4*)(p + 4);
            union { unsigned u[4]; f16x8 v; } t;
            t.u[0] = pk16(e0.x, e0.y); t.u[1] = pk16(e0.z, e0.w);
            t.u[2] = pk16(e1.x, e1.y); t.u[3] = pk16(e1.z, e1.w);
            Wf[jt][kc] = t.v;
        }

    // LDS addresses (fp16-element units). Row m = l16 (256B), 16 chunks of 16B,
    // chunk index XOR-swizzled with m. Reads: full chunk (kc*4+quad)^m.
    // Writes: 8B half-chunk; j-start = 32w+16jt+4quad -> chunk 4w+2jt+(quad>>1).
    const int raddr0 = l16 * 128 + ((((0 * 4 + quad) ^ l16) & 15) << 3);
    const int raddr1 = l16 * 128 + ((((1 * 4 + quad) ^ l16) & 15) << 3);
    const int raddr2 = l16 * 128 + ((((2 * 4 + quad) ^ l16) & 15) << 3);
    const int raddr3 = l16 * 128 + ((((3 * 4 + quad) ^ l16) & 15) << 3);
    const int waddr0 = l16 * 128 + ((((4 * wave + 0 + (quad >> 1)) ^ l16) & 15) << 3) + ((quad & 1) << 2);
    const int waddr1 = l16 * 128 + ((((4 * wave + 2 + (quad >> 1)) ^ l16) & 15) << 3) + ((quad & 1) << 2);

    // xp pointer for this lane: row fixed, j-base = 32*wave + quad*4 (+16 for jt1)
    const float* xpb = ws + (size_t)row * (TSTEPS * HID) + 32 * wave + quad * 4;

    // C init = xp_0 (h_{-1}=0); prefetch xp_1..3
    f32x4 C0, C1, xa0, xa1, xb0, xb1, xc0, xc1, xd0, xd1;
    C0  = *(const f32x4*)(xpb);
    C1  = *(const f32x4*)(xpb + 16);
    xb0 = *(const f32x4*)(xpb + 1 * HID); xb1 = *(const f32x4*)(xpb + 1 * HID + 16);
    xc0 = *(const f32x4*)(xpb + 2 * HID); xc1 = *(const f32x4*)(xpb + 2 * HID + 16);
    xd0 = *(const f32x4*)(xpb + 3 * HID); xd1 = *(const f32x4*)(xpb + 3 * HID + 16);

    for (int t = 0; t < 508; t += 4) {
        RSTEP(t,     xa0, xa1, xb0, xb1, 0);
        RSTEP(t + 1, xb0, xb1, xc0, xc1, 1);
        RSTEP(t + 2, xc0, xc1, xd0, xd1, 0);
        RSTEP(t + 3, xd0, xd1, xa0, xa1, 1);
    }
    RSTEP(508, xa0, xa1, xb0, xb1, 0);
    RSTEP(509, xb0, xb1, xc0, xc1, 1);
    RSTEP(510, xc0, xc1, xd0, xd1, 0);

    // h_511 -> stash fp32 over xp[row][0][:] (this block's own rows, contiguous j)
    f32x4 o0, o1;
    o0.x = tanh_fast(C0.x); o0.y = tanh_fast(C0.y);
    o0.z = tanh_fast(C0.z); o0.w = tanh_fast(C0.w);
    o1.x = tanh_fast(C1.x); o1.y = tanh_fast(C1.y);
    o1.z = tanh_fast(C1.z); o1.w = tanh_fast(C1.w);
    *(f32x4*)(ws + (size_t)row * (TSTEPS * HID) + 32 * wave + quad * 4)      = o0;
    *(f32x4*)(ws + (size_t)row * (TSTEPS * HID) + 32 * wave + 16 + quad * 4) = o1;
}
#undef RSTEP

// ---------------- Kernel 3: out = h_last @ W_fc^T + b_fc --------------------
__global__ __launch_bounds__(256) void k_fc(const float* __restrict__ ws,
                                            const float* __restrict__ Wfc,
                                            const float* __restrict__ bfc,
                                            float* __restrict__ out) {
    __shared__ float hb[HID];
    const int b   = blockIdx.x;
    const int tid = threadIdx.x;
    if (tid < HID) hb[tid] = ws[(size_t)b * (TSTEPS * HID) + tid];
    __syncthreads();

    for (int o = tid; o < ODIM; o += 256) {
        const float* wr = Wfc + (size_t)o * HID;
        float acc = 0.f;
#pragma unroll
        for (int q = 0; q < 32; q++) {
            float4 wv = *(const float4*)(wr + q * 4);
            float4 hv = *(const float4*)&hb[q * 4];
            acc += wv.x * hv.x + wv.y * hv.y + wv.z * hv.z + wv.w * hv.w;
        }
        out[(size_t)b * ODIM + o] = acc + bfc[o];
    }
}

extern "C" void kernel_launch(void* const* d_in, const int* in_sizes, int n_in,
                              void* d_out, int out_size, void* d_ws, size_t ws_size,
                              hipStream_t stream) {
    const float* x   = (const float*)d_in[0];
    const float* Wih = (const float*)d_in[1];
    const float* Whh = (const float*)d_in[2];
    const float* bih = (const float*)d_in[3];
    const float* bhh = (const float*)d_in[4];
    const float* Wfc = (const float*)d_in[5];
    const float* bfc = (const float*)d_in[6];
    float* out = (float*)d_out;
    float* ws  = (float*)d_ws;  // 64 MiB xp

    k_phase1<<<dim3(1024), dim3(256), 0, stream>>>(x, Wih, bih, bhh, ws);
    k_rnn   <<<dim3(16),   dim3(256), 0, stream>>>(Whh, ws);
    k_fc    <<<dim3(BATCH), dim3(256), 0, stream>>>(ws, Wfc, bfc, out);
}

// Round 2
// 392.597 us; speedup vs baseline: 1.0782x; 1.0782x over previous
//
#include <hip/hip_runtime.h>

// RNN: B=256, T=512, I=256, H=128, O=1000, fp32 in/out.
// Internals in fp16 (11-bit mantissa): W,x,h at 2^-12 rel err -> absmax ~4e-3,
// threshold 3.3e-2. Single MFMA product per tile (no hi/lo split).
// ws: xp[131072][128] fp32 = 64 MiB. h_last[r] overwrites xp[r*512+0][:] after
// the recurrence (each block's own rows, consumed at t=0 long before).

#define HID    128
#define TSTEPS 512
#define BATCH  256
#define INDIM  256
#define ODIM   1000

typedef _Float16 f16x8 __attribute__((ext_vector_type(8)));
typedef __fp16   fp16x2 __attribute__((ext_vector_type(2)));
typedef float    f32x4 __attribute__((ext_vector_type(4)));

__device__ __forceinline__ unsigned pk16(float a, float b) {
    union { fp16x2 h; unsigned u; } t;
    t.h = __builtin_amdgcn_cvt_pkrtz(a, b);   // packs 2 fp32 -> 2 fp16 (RTZ)
    return t.u;
}
// tanh without clamp: exp2 overflow->inf->rcp->0 gives +1; underflow->0 gives -1.
__device__ __forceinline__ float tanh_fast(float v) {
    float e = __expf(2.f * v);                 // v_mul + v_exp_f32
    float r = __builtin_amdgcn_rcpf(e + 1.f);  // v_add + v_rcp_f32
    return __builtin_fmaf(-2.f, r, 1.f);
}

// ---------------- Kernel 1: xp = x @ W_ih^T + (b_ih + b_hh) ----------------
// MFMA 16x16x32 f16, double-buffered LDS staging, fp16 conversion at stage time.
// LDS tile rows = 32 k-elems (64B) = four 16B chunks, XOR-swizzled c ^= (row&3).
__global__ __launch_bounds__(256) void k_phase1(const float* __restrict__ x,
                                                const float* __restrict__ Wih,
                                                const float* __restrict__ bih,
                                                const float* __restrict__ bhh,
                                                float* __restrict__ xp) {
    __shared__ __align__(16) _Float16 xs[2][4096];   // x tile fp16
    __shared__ __align__(16) _Float16 wsm[2][4096];  // W tile fp16

    const int tid  = threadIdx.x;
    const int wave = tid >> 6, lane = tid & 63;
    const int quad = lane >> 4, l16 = lane & 15;
    const int wm = wave >> 1, wn = wave & 1;
    const int m0 = blockIdx.x * 128;

    // staging geometry: li = q*256+tid -> row = li>>3 (0..127), c = li&7 (4-float units)
    int srow[4], scol[4], sdst[4];
#pragma unroll
    for (int q = 0; q < 4; q++) {
        int li = q * 256 + tid;
        srow[q] = li >> 3;
        scol[q] = li & 7;
        sdst[q] = srow[q] * 32 + ((((scol[q] >> 1) ^ srow[q]) & 3) << 3) + ((scol[q] & 1) << 2);
    }

    float bias_v[4];
#pragma unroll
    for (int nt = 0; nt < 4; nt++) {
        int j = wn * 64 + nt * 16 + l16;
        bias_v[nt] = bih[j] + bhh[j];
    }

    float4 rx[4], rw[4];
#define LOAD_STAGE(KC)                                                              \
    {                                                                               \
        _Pragma("unroll") for (int q = 0; q < 4; q++) {                             \
            rx[q] = *(const float4*)(x + (size_t)(m0 + srow[q]) * INDIM + (KC) * 32 + scol[q] * 4); \
            rw[q] = *(const float4*)(Wih + (size_t)srow[q] * INDIM + (KC) * 32 + scol[q] * 4);      \
        }                                                                           \
    }
#define WRITE_STAGE(BUF)                                                            \
    {                                                                               \
        _Pragma("unroll") for (int q = 0; q < 4; q++) {                             \
            uint2 px, pw;                                                           \
            px.x = pk16(rx[q].x, rx[q].y); px.y = pk16(rx[q].z, rx[q].w);           \
            pw.x = pk16(rw[q].x, rw[q].y); pw.y = pk16(rw[q].z, rw[q].w);           \
            *(uint2*)&xs[BUF][sdst[q]]  = px;                                       \
            *(uint2*)&wsm[BUF][sdst[q]] = pw;                                       \
        }                                                                           \
    }

    f32x4 acc[4][4];
#pragma unroll
    for (int mt = 0; mt < 4; mt++)
#pragma unroll
        for (int nt = 0; nt < 4; nt++) {
            acc[mt][nt].x = 0.f; acc[mt][nt].y = 0.f;
            acc[mt][nt].z = 0.f; acc[mt][nt].w = 0.f;
        }

    LOAD_STAGE(0);
    WRITE_STAGE(0);
    __syncthreads();

    for (int kc = 0; kc < 8; kc++) {
        const int b = kc & 1;
        if (kc < 7) LOAD_STAGE(kc + 1);

        f16x8 a[4], bw[4];
#pragma unroll
        for (int mt = 0; mt < 4; mt++) {
            int row = wm * 64 + mt * 16 + l16;
            a[mt] = *(const f16x8*)&xs[b][row * 32 + (((quad ^ row) & 3) << 3)];
        }
#pragma unroll
        for (int nt = 0; nt < 4; nt++) {
            int row = wn * 64 + nt * 16 + l16;
            bw[nt] = *(const f16x8*)&wsm[b][row * 32 + (((quad ^ row) & 3) << 3)];
        }
#pragma unroll
        for (int mt = 0; mt < 4; mt++)
#pragma unroll
            for (int nt = 0; nt < 4; nt++)
                acc[mt][nt] = __builtin_amdgcn_mfma_f32_16x16x32_f16(a[mt], bw[nt], acc[mt][nt], 0, 0, 0);

        if (kc < 7) WRITE_STAGE(b ^ 1);
        __syncthreads();
    }

    // C layout: col = l16, row = quad*4 + reg
#pragma unroll
    for (int mt = 0; mt < 4; mt++)
#pragma unroll
        for (int nt = 0; nt < 4; nt++)
#pragma unroll
            for (int reg = 0; reg < 4; reg++) {
                int row = m0 + wm * 64 + mt * 16 + quad * 4 + reg;
                xp[(size_t)row * HID + wn * 64 + nt * 16 + l16] = acc[mt][nt][reg] + bias_v[nt];
            }
#undef LOAD_STAGE
#undef WRITE_STAGE
}

// ---------------- Kernel 2: recurrence (MFMA f16, 8 waves) ------------------
// 16 blocks x 512 thr. Block b: rows [16b,16b+16). Wave w: j in [16w,16w+16).
// W_hh fp16 persistent in VGPRs (16 regs). h in LDS fp16, 2 planes, 1 barrier
// per step. Row = 128 fp16 = 256B = 16 chunks of 16B, XOR-swizzled c ^= (m&15):
// b128 A-frag reads conflict-free (verified 0 conflicts), b16 writes 2-way max
// (free). Two parallel MFMA chains of 2 halve chain latency.
// Barrier is raw asm `s_waitcnt lgkmcnt(0); s_barrier` -- NO vmcnt drain
// (unlike __syncthreads), so the xp prefetch (issued 4 steps ahead, consumed
// with 3-step slack ~2000cy) genuinely stays in flight; compiler emits a
// counted vmcnt before the consuming MFMA only. lgkmcnt(0) still publishes
// this step's h-writes and drains this wave's plane reads before the barrier,
// so the 2-plane rotation stays race-free (plane P written at t+2 only after
// barrier t+1, which every wave reaches only after its plane-P reads at t).
#define RNN_STEP4(TV, XQI, XQC, PB) {                                             \
    _Pragma("unroll") for (int reg = 0; reg < 4; reg++) {                         \
        float hv = tanh_fast(C[reg]);                                             \
        int m = quad * 4 + reg;                                                   \
        hp[PB][m * 128 + ((((jbase >> 3) ^ m) & 15) << 3) + (jbase & 7)] =        \
            (_Float16)hv;                                                         \
    }                                                                             \
    if ((TV) + 4 < TSTEPS) {                                                      \
        _Pragma("unroll") for (int reg = 0; reg < 4; reg++)                       \
            XQI[reg] = xpb[ib[reg] + ((TV) + 4) * HID];                           \
    }                                                                             \
    asm volatile("s_waitcnt lgkmcnt(0)\n\ts_barrier" ::: "memory");               \
    f16x8 A[4];                                                                   \
    _Pragma("unroll") for (int kc = 0; kc < 4; kc++)                              \
        A[kc] = *(const f16x8*)&hp[PB][l16 * 128 + ((((kc * 4 + quad) ^ l16) & 15) << 3)]; \
    f32x4 ch, cl;                                                                 \
    ch.x = XQC[0]; ch.y = XQC[1]; ch.z = XQC[2]; ch.w = XQC[3];                   \
    cl.x = 0.f; cl.y = 0.f; cl.z = 0.f; cl.w = 0.f;                               \
    ch = __builtin_amdgcn_mfma_f32_16x16x32_f16(A[0], Bf[0], ch, 0, 0, 0);        \
    cl = __builtin_amdgcn_mfma_f32_16x16x32_f16(A[2], Bf[2], cl, 0, 0, 0);        \
    ch = __builtin_amdgcn_mfma_f32_16x16x32_f16(A[1], Bf[1], ch, 0, 0, 0);        \
    cl = __builtin_amdgcn_mfma_f32_16x16x32_f16(A[3], Bf[3], cl, 0, 0, 0);        \
    C = ch + cl;                                                                  \
}

__global__ __launch_bounds__(512) void k_rnn4(const float* __restrict__ Whh,
                                              float* __restrict__ ws) {
    __shared__ __align__(16) _Float16 hp[2][16 * 128];
    const int tid  = threadIdx.x;
    const int wave = tid >> 6, lane = tid & 63;
    const int quad = lane >> 4, l16 = lane & 15;
    const int r0    = blockIdx.x * 16;
    const int jbase = wave * 16 + l16;   // this thread's output j (0..127)

    // W_hh B-frags fp16: n = jbase, k = kc*32 + quad*8 + i
    f16x8 Bf[4];
#pragma unroll
    for (int kc = 0; kc < 4; kc++) {
        const float* p = Whh + (size_t)jbase * HID + kc * 32 + quad * 8;
        float4 e0 = *(const float4*)p, e1 = *(const float4*)(p + 4);
        union { unsigned u[4]; f16x8 v; } t;
        t.u[0] = pk16(e0.x, e0.y); t.u[1] = pk16(e0.z, e0.w);
        t.u[2] = pk16(e1.x, e1.y); t.u[3] = pk16(e1.z, e1.w);
        Bf[kc] = t.v;
    }

    const float* xpb = ws;
    int ib[4];
#pragma unroll
    for (int reg = 0; reg < 4; reg++)
        ib[reg] = (r0 + quad * 4 + reg) * (TSTEPS * HID) + jbase;

    // C init = xp_0 (h_{-1}=0); prefetch xp_1..3
    f32x4 C;
    float xq0[4], xq1[4], xq2[4], xq3[4];
    C.x = xpb[ib[0]]; C.y = xpb[ib[1]]; C.z = xpb[ib[2]]; C.w = xpb[ib[3]];
#pragma unroll
    for (int reg = 0; reg < 4; reg++) {
        xq1[reg] = xpb[ib[reg] + 1 * HID];
        xq2[reg] = xpb[ib[reg] + 2 * HID];
        xq3[reg] = xpb[ib[reg] + 3 * HID];
    }

    for (int t = 0; t < 508; t += 4) {
        RNN_STEP4(t,     xq0, xq1, 0);
        RNN_STEP4(t + 1, xq1, xq2, 1);
        RNN_STEP4(t + 2, xq2, xq3, 0);
        RNN_STEP4(t + 3, xq3, xq0, 1);
    }
    RNN_STEP4(508, xq0, xq1, 0);
    RNN_STEP4(509, xq1, xq2, 1);
    RNN_STEP4(510, xq2, xq3, 0);

    // h_511 -> stash fp32 over xp[r][0][:] (this block's own rows)
#pragma unroll
    for (int reg = 0; reg < 4; reg++)
        ws[ib[reg]] = tanh_fast(C[reg]);
}

// ---------------- Kernel 3: out = h_last @ W_fc^T + b_fc --------------------
__global__ __launch_bounds__(256) void k_fc(const float* __restrict__ ws,
                                            const float* __restrict__ Wfc,
                                            const float* __restrict__ bfc,
                                            float* __restrict__ out) {
    __shared__ float hb[HID];
    const int b   = blockIdx.x;
    const int tid = threadIdx.x;
    if (tid < HID) hb[tid] = ws[(size_t)b * (TSTEPS * HID) + tid];
    __syncthreads();

    for (int o = tid; o < ODIM; o += 256) {
        const float* wr = Wfc + (size_t)o * HID;
        float acc = 0.f;
#pragma unroll
        for (int q = 0; q < 32; q++) {
            float4 wv = *(const float4*)(wr + q * 4);
            float4 hv = *(const float4*)&hb[q * 4];
            acc += wv.x * hv.x + wv.y * hv.y + wv.z * hv.z + wv.w * hv.w;
        }
        out[(size_t)b * ODIM + o] = acc + bfc[o];
    }
}

extern "C" void kernel_launch(void* const* d_in, const int* in_sizes, int n_in,
                              void* d_out, int out_size, void* d_ws, size_t ws_size,
                              hipStream_t stream) {
    const float* x   = (const float*)d_in[0];
    const float* Wih = (const float*)d_in[1];
    const float* Whh = (const float*)d_in[2];
    const float* bih = (const float*)d_in[3];
    const float* bhh = (const float*)d_in[4];
    const float* Wfc = (const float*)d_in[5];
    const float* bfc = (const float*)d_in[6];
    float* out = (float*)d_out;
    float* ws  = (float*)d_ws;  // 64 MiB xp

    k_phase1<<<dim3(1024), dim3(256), 0, stream>>>(x, Wih, bih, bhh, ws);
    k_rnn4  <<<dim3(16),   dim3(512), 0, stream>>>(Whh, ws);
    k_fc    <<<dim3(BATCH), dim3(256), 0, stream>>>(ws, Wfc, bfc, out);
}

// Round 4
// 375.404 us; speedup vs baseline: 1.1276x; 1.0458x over previous
//
#include <hip/hip_runtime.h>

// RNN: B=256, T=512, I=256, H=128, O=1000, fp32 in/out.
// Internals in fp16 (11-bit mantissa): W,x,h at 2^-12 rel err -> absmax ~4e-3,
// threshold 3.3e-2. Single MFMA product per tile (no hi/lo split).
// ws: xp[131072][128] fp32 = 64 MiB. h_last[r] overwrites xp[r*512+0][:] after
// the recurrence (each block's own rows, consumed at t=0 long before).

#define HID    128
#define TSTEPS 512
#define BATCH  256
#define INDIM  256
#define ODIM   1000

typedef _Float16 f16x8 __attribute__((ext_vector_type(8)));
typedef __fp16   fp16x2 __attribute__((ext_vector_type(2)));
typedef float    f32x4 __attribute__((ext_vector_type(4)));

__device__ __forceinline__ unsigned pk16(float a, float b) {
    union { fp16x2 h; unsigned u; } t;
    t.h = __builtin_amdgcn_cvt_pkrtz(a, b);   // packs 2 fp32 -> 2 fp16 (RTZ)
    return t.u;
}
// tanh without clamp: exp2 overflow->inf->rcp->0 gives +1; underflow->0 gives -1.
__device__ __forceinline__ float tanh_fast(float v) {
    float e = __expf(2.f * v);                 // v_mul + v_exp_f32
    float r = __builtin_amdgcn_rcpf(e + 1.f);  // v_add + v_rcp_f32
    return __builtin_fmaf(-2.f, r, 1.f);
}

// ---------------- Kernel 1: xp = x @ W_ih^T + (b_ih + b_hh) ----------------
// MFMA 16x16x32 f16, double-buffered LDS staging, fp16 conversion at stage time.
// LDS tile rows = 32 k-elems (64B) = four 16B chunks, XOR-swizzled c ^= (row&3).
// Operand-swapped epilogue: acc = mfma(W-frag, x-frag) puts col(l16)=x-row m,
// row(quad*4+reg)=j -> lane holds 4 consecutive j at fixed m: C-write is 16
// dwordx4 (vs 64 scalar dword), bias add vectorized.
__global__ __launch_bounds__(256) void k_phase1(const float* __restrict__ x,
                                                const float* __restrict__ Wih,
                                                const float* __restrict__ bih,
                                                const float* __restrict__ bhh,
                                                float* __restrict__ xp) {
    __shared__ __align__(16) _Float16 xs[2][4096];   // x tile fp16
    __shared__ __align__(16) _Float16 wsm[2][4096];  // W tile fp16

    const int tid  = threadIdx.x;
    const int wave = tid >> 6, lane = tid & 63;
    const int quad = lane >> 4, l16 = lane & 15;
    const int wm = wave >> 1, wn = wave & 1;
    const int m0 = blockIdx.x * 128;

    // staging geometry: li = q*256+tid -> row = li>>3 (0..127), c = li&7 (4-float units)
    int srow[4], scol[4], sdst[4];
#pragma unroll
    for (int q = 0; q < 4; q++) {
        int li = q * 256 + tid;
        srow[q] = li >> 3;
        scol[q] = li & 7;
        sdst[q] = srow[q] * 32 + ((((scol[q] >> 1) ^ srow[q]) & 3) << 3) + ((scol[q] & 1) << 2);
    }

    // bias for this lane's 4 consecutive j: j0 = wn*64 + nt*16 + quad*4
    f32x4 bias_v[4];
#pragma unroll
    for (int nt = 0; nt < 4; nt++) {
        int j0 = wn * 64 + nt * 16 + quad * 4;
        bias_v[nt] = *(const f32x4*)(bih + j0) + *(const f32x4*)(bhh + j0);
    }

    float4 rx[4], rw[4];
#define LOAD_STAGE(KC)                                                              \
    {                                                                               \
        _Pragma("unroll") for (int q = 0; q < 4; q++) {                             \
            rx[q] = *(const float4*)(x + (size_t)(m0 + srow[q]) * INDIM + (KC) * 32 + scol[q] * 4); \
            rw[q] = *(const float4*)(Wih + (size_t)srow[q] * INDIM + (KC) * 32 + scol[q] * 4);      \
        }                                                                           \
    }
#define WRITE_STAGE(BUF)                                                            \
    {                                                                               \
        _Pragma("unroll") for (int q = 0; q < 4; q++) {                             \
            uint2 px, pw;                                                           \
            px.x = pk16(rx[q].x, rx[q].y); px.y = pk16(rx[q].z, rx[q].w);           \
            pw.x = pk16(rw[q].x, rw[q].y); pw.y = pk16(rw[q].z, rw[q].w);           \
            *(uint2*)&xs[BUF][sdst[q]]  = px;                                       \
            *(uint2*)&wsm[BUF][sdst[q]] = pw;                                       \
        }                                                                           \
    }

    f32x4 acc[4][4];
#pragma unroll
    for (int mt = 0; mt < 4; mt++)
#pragma unroll
        for (int nt = 0; nt < 4; nt++) {
            acc[mt][nt].x = 0.f; acc[mt][nt].y = 0.f;
            acc[mt][nt].z = 0.f; acc[mt][nt].w = 0.f;
        }

    LOAD_STAGE(0);
    WRITE_STAGE(0);
    __syncthreads();

    for (int kc = 0; kc < 8; kc++) {
        const int b = kc & 1;
        if (kc < 7) LOAD_STAGE(kc + 1);

        f16x8 a[4], bw[4];
#pragma unroll
        for (int mt = 0; mt < 4; mt++) {
            int row = wm * 64 + mt * 16 + l16;
            a[mt] = *(const f16x8*)&xs[b][row * 32 + (((quad ^ row) & 3) << 3)];
        }
#pragma unroll
        for (int nt = 0; nt < 4; nt++) {
            int row = wn * 64 + nt * 16 + l16;
            bw[nt] = *(const f16x8*)&wsm[b][row * 32 + (((quad ^ row) & 3) << 3)];
        }
        // swapped: A-operand = W (i=j), B-operand = x (j-col = m)
#pragma unroll
        for (int mt = 0; mt < 4; mt++)
#pragma unroll
            for (int nt = 0; nt < 4; nt++)
                acc[mt][nt] = __builtin_amdgcn_mfma_f32_16x16x32_f16(bw[nt], a[mt], acc[mt][nt], 0, 0, 0);

        if (kc < 7) WRITE_STAGE(b ^ 1);
        __syncthreads();
    }

    // Swapped C layout: col(l16) = x-row m, row(quad*4+reg) = j.
    // Lane stores 4 consecutive j at its row -> one dwordx4 per (mt,nt).
#pragma unroll
    for (int mt = 0; mt < 4; mt++) {
        int row = m0 + wm * 64 + mt * 16 + l16;
#pragma unroll
        for (int nt = 0; nt < 4; nt++) {
            int col = wn * 64 + nt * 16 + quad * 4;
            *(f32x4*)&xp[(size_t)row * HID + col] = acc[mt][nt] + bias_v[nt];
        }
    }
#undef LOAD_STAGE
#undef WRITE_STAGE
}

// ---------------- Kernel 2: recurrence (MFMA f16, 8 waves, swapped) ---------
// 16 blocks x 512 thr. Block b: rows [16b,16b+16). Wave w: j in [16w,16w+16).
// Operand-swapped MFMA: D[j][m] = sum_k W[j][k] h[m][k]. A = W_hh persistent
// in VGPRs (16 regs, load pattern identical to previous Bf). B = h from LDS:
// read pattern BYTE-IDENTICAL to the proven conflict-free raddr (b128,
// XOR-chunk swizzle c ^= l16). C layout: col(l16)=m, row(quad*4+reg)=j ->
// lane's 4 acc regs are CONSECUTIVE j at fixed m:
//   h-write:  one ds_write_b64 (vs 4x ds_write_b16)  [2-way banked = free]
//   xp load:  one dwordx4      (vs 4 scalar dword)
//   cvt:      two cvt_pkrtz    (vs 4 v_cvt_f16_f32)
//   C-init:   vector copy      (vs 4 scalar moves)
// Same 2-plane rotation, 1 raw barrier per step (lgkmcnt(0) only - neutral vs
// __syncthreads per round-2 A/B, kept since it is never worse).
#define RNN_STEP4(TV, XQI, XQC, PB) {                                             \
    uint2 pw;                                                                     \
    pw.x = pk16(tanh_fast(C.x), tanh_fast(C.y));                                  \
    pw.y = pk16(tanh_fast(C.z), tanh_fast(C.w));                                  \
    *(uint2*)&hp[PB][waddr] = pw;                                                 \
    if ((TV) + 4 < TSTEPS)                                                        \
        XQI = *(const f32x4*)(xpb + ((TV) + 4) * HID);                            \
    asm volatile("s_waitcnt lgkmcnt(0)\n\ts_barrier" ::: "memory");               \
    f16x8 H0 = *(const f16x8*)&hp[PB][raddr0];                                    \
    f16x8 H1 = *(const f16x8*)&hp[PB][raddr1];                                    \
    f16x8 H2 = *(const f16x8*)&hp[PB][raddr2];                                    \
    f16x8 H3 = *(const f16x8*)&hp[PB][raddr3];                                    \
    f32x4 ch = XQC, cl;                                                           \
    cl.x = 0.f; cl.y = 0.f; cl.z = 0.f; cl.w = 0.f;                               \
    ch = __builtin_amdgcn_mfma_f32_16x16x32_f16(Wf[0], H0, ch, 0, 0, 0);          \
    cl = __builtin_amdgcn_mfma_f32_16x16x32_f16(Wf[2], H2, cl, 0, 0, 0);          \
    ch = __builtin_amdgcn_mfma_f32_16x16x32_f16(Wf[1], H1, ch, 0, 0, 0);          \
    cl = __builtin_amdgcn_mfma_f32_16x16x32_f16(Wf[3], H3, cl, 0, 0, 0);          \
    C = ch + cl;                                                                  \
}

__global__ __launch_bounds__(512) void k_rnn4(const float* __restrict__ Whh,
                                              float* __restrict__ ws) {
    __shared__ __align__(16) _Float16 hp[2][16 * 128];
    const int tid  = threadIdx.x;
    const int wave = tid >> 6, lane = tid & 63;
    const int quad = lane >> 4, l16 = lane & 15;
    const int r0   = blockIdx.x * 16;

    // A-frags (persistent W_hh): A[i=l16 -> j=16w+l16][k = kc*32 + quad*8 + i]
    f16x8 Wf[4];
#pragma unroll
    for (int kc = 0; kc < 4; kc++) {
        const float* p = Whh + (size_t)(16 * wave + l16) * HID + kc * 32 + quad * 8;
        float4 e0 = *(const float4*)p, e1 = *(const float4*)(p + 4);
        union { unsigned u[4]; f16x8 v; } t;
        t.u[0] = pk16(e0.x, e0.y); t.u[1] = pk16(e0.z, e0.w);
        t.u[2] = pk16(e1.x, e1.y); t.u[3] = pk16(e1.z, e1.w);
        Wf[kc] = t.v;
    }

    // LDS addrs (fp16-elem units). h row m = l16 (256B = 16 chunks of 16B),
    // chunk XOR-swizzled with l16. Reads: full chunk (kc*4+quad)^l16 (= the
    // proven conflict-free pattern). Write: this lane's j-quad (j=16w+4q..+3)
    // = 8B at chunk 2w+(q>>1), half (q&1).
    const int raddr0 = l16 * 128 + ((((0 * 4 + quad) ^ l16) & 15) << 3);
    const int raddr1 = l16 * 128 + ((((1 * 4 + quad) ^ l16) & 15) << 3);
    const int raddr2 = l16 * 128 + ((((2 * 4 + quad) ^ l16) & 15) << 3);
    const int raddr3 = l16 * 128 + ((((3 * 4 + quad) ^ l16) & 15) << 3);
    const int waddr  = l16 * 128 + ((((2 * wave + (quad >> 1)) ^ l16) & 15) << 3) + ((quad & 1) << 2);

    // xp base for this lane: batch row r0+l16, j-base = 16*wave + 4*quad
    const float* xpb = ws + (size_t)(r0 + l16) * (TSTEPS * HID) + 16 * wave + 4 * quad;

    // C init = xp_0 (h_{-1}=0); prefetch xp_1..3 (one dwordx4 each)
    f32x4 C, xq0, xq1, xq2, xq3;
    C   = *(const f32x4*)(xpb);
    xq1 = *(const f32x4*)(xpb + 1 * HID);
    xq2 = *(const f32x4*)(xpb + 2 * HID);
    xq3 = *(const f32x4*)(xpb + 3 * HID);

    for (int t = 0; t < 508; t += 4) {
        RNN_STEP4(t,     xq0, xq1, 0);
        RNN_STEP4(t + 1, xq1, xq2, 1);
        RNN_STEP4(t + 2, xq2, xq3, 0);
        RNN_STEP4(t + 3, xq3, xq0, 1);
    }
    RNN_STEP4(508, xq0, xq1, 0);
    RNN_STEP4(509, xq1, xq2, 1);
    RNN_STEP4(510, xq2, xq3, 0);

    // h_511 -> stash fp32 over xp[row][0][:] (this block's own rows), one dwordx4
    f32x4 o;
    o.x = tanh_fast(C.x); o.y = tanh_fast(C.y);
    o.z = tanh_fast(C.z); o.w = tanh_fast(C.w);
    *(f32x4*)(ws + (size_t)(r0 + l16) * (TSTEPS * HID) + 16 * wave + 4 * quad) = o;
}
#undef RNN_STEP4

// ---------------- Kernel 3: out = h_last @ W_fc^T + b_fc --------------------
__global__ __launch_bounds__(256) void k_fc(const float* __restrict__ ws,
                                            const float* __restrict__ Wfc,
                                            const float* __restrict__ bfc,
                                            float* __restrict__ out) {
    __shared__ float hb[HID];
    const int b   = blockIdx.x;
    const int tid = threadIdx.x;
    if (tid < HID) hb[tid] = ws[(size_t)b * (TSTEPS * HID) + tid];
    __syncthreads();

    for (int o = tid; o < ODIM; o += 256) {
        const float* wr = Wfc + (size_t)o * HID;
        float acc = 0.f;
#pragma unroll
        for (int q = 0; q < 32; q++) {
            float4 wv = *(const float4*)(wr + q * 4);
            float4 hv = *(const float4*)&hb[q * 4];
            acc += wv.x * hv.x + wv.y * hv.y + wv.z * hv.z + wv.w * hv.w;
        }
        out[(size_t)b * ODIM + o] = acc + bfc[o];
    }
}

extern "C" void kernel_launch(void* const* d_in, const int* in_sizes, int n_in,
                              void* d_out, int out_size, void* d_ws, size_t ws_size,
                              hipStream_t stream) {
    const float* x   = (const float*)d_in[0];
    const float* Wih = (const float*)d_in[1];
    const float* Whh = (const float*)d_in[2];
    const float* bih = (const float*)d_in[3];
    const float* bhh = (const float*)d_in[4];
    const float* Wfc = (const float*)d_in[5];
    const float* bfc = (const float*)d_in[6];
    float* out = (float*)d_out;
    float* ws  = (float*)d_ws;  // 64 MiB xp

    k_phase1<<<dim3(1024), dim3(256), 0, stream>>>(x, Wih, bih, bhh, ws);
    k_rnn4  <<<dim3(16),   dim3(512), 0, stream>>>(Whh, ws);
    k_fc    <<<dim3(BATCH), dim3(256), 0, stream>>>(ws, Wfc, bfc, out);
}